// Round 2
// baseline (174.769 us; speedup 1.0000x reference)
//
#include <hip/hip_runtime.h>
#include <math.h>

// Only out[mask_idx] (320 agent nodes of 50000) is read downstream, so only
// edges whose dst is a masked node matter (~5120 of 800000). We compact those
// and skip 99.4% of the reference's work.
//
// Workspace discipline (round-1 post-mortem): total footprint must be small —
// a 6.8 MB layout overran ws_size and corrupted the harness's pristine input
// copies (first call correct, all later calls consistently wrong). Now ~160 KB,
// clamped to ws_size.

#define HASH_CAP  1024
#define HASH_MASK 1023
__device__ __forceinline__ unsigned hash_node(int n) {
    return ((unsigned)n * 2654435761u) & HASH_MASK;
}

// Build node -> agent-slot hash (open addressing, load factor <= 0.32).
__global__ void k_build(const int* __restrict__ mask_idx, int A,
                        int* __restrict__ hkey, int* __restrict__ hval) {
    int a = blockIdx.x * blockDim.x + threadIdx.x;
    if (a >= A) return;
    int node = mask_idx[a];
    unsigned h = hash_node(node);
    while (true) {
        int old = atomicCAS(&hkey[h], -1, node);
        if (old == -1) { hval[h] = a; break; }   // claimed this slot
        if (old == node) break;                  // duplicate node: reuse winner's slot
        h = (h + 1) & HASH_MASK;
    }
}

// Scan all edges; compact (edge, slot) pairs whose dst is masked; count degree.
__global__ void k_scan(const int* __restrict__ dstp, int E,
                       const int* __restrict__ hkey, const int* __restrict__ hval,
                       int* __restrict__ cnt, int* __restrict__ list2, int cap,
                       int* __restrict__ deg_c) {
    int e = blockIdx.x * blockDim.x + threadIdx.x;
    if (e >= E) return;
    int d = dstp[e];
    unsigned h = hash_node(d);
    int s = -1;
    while (true) {
        int k = hkey[h];
        if (k == -1) break;
        if (k == d) { s = hval[h]; break; }
        h = (h + 1) & HASH_MASK;
    }
    if (s >= 0) {
        int p = atomicAdd(cnt, 1);
        if (p < cap) { list2[2 * p] = e; list2[2 * p + 1] = s; }
        atomicAdd(&deg_c[s], 1);
    }
}

// Process compacted active edges. Block = 256 threads = 16 edges x 16 out-lanes.
__global__ __launch_bounds__(256) void k_edges(
    const int* __restrict__ srcp,
    const float* __restrict__ x, const float* __restrict__ edge_attr,
    const float* __restrict__ w1, const float* __restrict__ b1,
    const float* __restrict__ w2, const float* __restrict__ b2,
    const int* __restrict__ cnt, const int* __restrict__ list2, int cap,
    float* __restrict__ aggr_c) {
    __shared__ float s_w2[4096];   // [16 j][256 io]
    __shared__ float s_b2[256];
    __shared__ float s_w1[128];    // [8 k][16 j]
    __shared__ float s_b1[16];
    __shared__ float s_ea[16][8];
    __shared__ float s_x[16][16];
    __shared__ float s_h[16][16];
    __shared__ int   s_e[16], s_slot[16];

    int tid = threadIdx.x;
    int n = *cnt; if (n > cap) n = cap;
    if ((int)(blockIdx.x * 16) >= n) return;   // uniform early-exit for idle blocks

    for (int k = tid; k < 4096; k += 256) s_w2[k] = w2[k];
    s_b2[tid] = b2[tid];                       // blockDim==256, b2 has 256 elems
    if (tid < 128) s_w1[tid] = w1[tid];
    if (tid < 16)  s_b1[tid] = b1[tid];
    __syncthreads();

    int el = tid >> 4;     // edge slot 0..15
    int o  = tid & 15;     // output channel 0..15

    for (int base = blockIdx.x * 16; base < n; base += gridDim.x * 16) {
        if (o == 0) {
            int idx = base + el;
            if (idx < n) {
                int e = list2[2 * idx];
                s_e[el] = e;
                s_slot[el] = list2[2 * idx + 1];
            } else s_e[el] = -1;
        }
        __syncthreads();
        int e = s_e[el];
        bool valid = (e >= 0);
        if (valid) {
            if (o < 8) s_ea[el][o] = edge_attr[(long)e * 8 + o];
            // src gather: re-read srcp[e] per lane group is cheap (L2 hit)
            s_x[el][o] = x[(long)srcp[e] * 16 + o];
        }
        __syncthreads();
        if (valid) {
            // h[el][o] = relu(b1[o] + ea . w1[:,o])
            float hj = s_b1[o];
            #pragma unroll
            for (int k = 0; k < 8; ++k) hj += s_ea[el][k] * s_w1[k * 16 + o];
            s_h[el][o] = hj > 0.f ? hj : 0.f;
        }
        __syncthreads();
        if (valid) {
            float hr[16], xr[16];
            #pragma unroll
            for (int j = 0; j < 16; ++j) hr[j] = s_h[el][j];
            #pragma unroll
            for (int i = 0; i < 16; ++i) xr[i] = s_x[el][i];
            // msg[o] = sum_i x_i * (b2[i,o] + sum_j h_j * w2[j, i*16+o])
            float m = 0.f;
            #pragma unroll
            for (int i = 0; i < 16; ++i) {
                float t = s_b2[i * 16 + o];
                #pragma unroll
                for (int j = 0; j < 16; ++j) t += hr[j] * s_w2[j * 256 + i * 16 + o];
                m += xr[i] * t;
            }
            atomicAdd(&aggr_c[s_slot[el] * 16 + o], m);
        }
        __syncthreads();
    }
}

// One block (1 wave, 64 threads) per agent: combine + 3-layer ELU MLP head.
__global__ __launch_bounds__(64) void k_head(
    const int* __restrict__ mask_idx, const float* __restrict__ action,
    const float* __restrict__ x,
    const int* __restrict__ hkey, const int* __restrict__ hval,
    const float* __restrict__ aggr_c, const int* __restrict__ deg_c,
    const float* __restrict__ root, const float* __restrict__ bias,
    const float* __restrict__ fc1_w, const float* __restrict__ fc1_b,
    const float* __restrict__ fc2_w, const float* __restrict__ fc2_b,
    const float* __restrict__ fc3_w, const float* __restrict__ fc3_b,
    float* __restrict__ out) {
    __shared__ float xm[17];
    __shared__ float y1[64];
    int a = blockIdx.x;
    int t = threadIdx.x;
    int node = mask_idx[a];
    // probe hash (node is guaranteed present; uniform across the wave)
    unsigned h = hash_node(node);
    int s;
    while (true) {
        int k = hkey[h];
        if (k == node) { s = hval[h]; break; }
        h = (h + 1) & HASH_MASK;
    }
    if (t < 16) {
        float r = bias[t];
        #pragma unroll
        for (int i = 0; i < 16; ++i) r += x[(long)node * 16 + i] * root[i * 16 + t];
        float dg = (float)deg_c[s];
        if (dg < 1.f) dg = 1.f;
        xm[t] = aggr_c[s * 16 + t] / dg + r;
    } else if (t == 16) {
        xm[16] = action[a];
    }
    __syncthreads();
    float v = fc1_b[t];
    #pragma unroll
    for (int k = 0; k < 17; ++k) v += xm[k] * fc1_w[k * 64 + t];
    v = v > 0.f ? v : expm1f(v);
    y1[t] = v;
    __syncthreads();
    float u = fc2_b[t];
    #pragma unroll
    for (int j = 0; j < 64; ++j) u += y1[j] * fc2_w[j * 64 + t];
    u = u > 0.f ? u : expm1f(u);
    float p = u * fc3_w[t];
    #pragma unroll
    for (int off = 32; off > 0; off >>= 1) p += __shfl_down(p, off, 64);
    if (t == 0) out[a] = p + fc3_b[0];
}

extern "C" void kernel_launch(void* const* d_in, const int* in_sizes, int n_in,
                              void* d_out, int out_size, void* d_ws, size_t ws_size,
                              hipStream_t stream) {
    const float* x      = (const float*)d_in[0];
    const int*   ei     = (const int*)  d_in[1];
    const float* ea     = (const float*)d_in[2];
    const int*   mask   = (const int*)  d_in[3];
    const float* action = (const float*)d_in[4];
    // d_in[5] = B (unused)
    const float* w1     = (const float*)d_in[6];
    const float* b1     = (const float*)d_in[7];
    const float* w2     = (const float*)d_in[8];
    const float* b2     = (const float*)d_in[9];
    const float* root   = (const float*)d_in[10];
    const float* bias   = (const float*)d_in[11];
    const float* fc1_w  = (const float*)d_in[12];
    const float* fc1_b  = (const float*)d_in[13];
    const float* fc2_w  = (const float*)d_in[14];
    const float* fc2_b  = (const float*)d_in[15];
    const float* fc3_w  = (const float*)d_in[16];
    const float* fc3_b  = (const float*)d_in[17];

    const int E = in_sizes[2] / 8;    // 800000
    const int A = in_sizes[4];        // 320

    const int* srcp = ei;
    const int* dstp = ei + E;

    // Workspace layout (ints): [hkey 1024][hval 1024][aggr_c A*16 f32][deg_c A]
    //                          [cnt 4][list2 pairs ...]
    int* hkey   = (int*)d_ws;
    int* hval   = hkey + HASH_CAP;
    float* aggr = (float*)(hval + HASH_CAP);
    int* deg_c  = (int*)(aggr + (size_t)A * 16);
    int* cnt    = deg_c + A;
    int* list2  = cnt + 4;

    size_t fixed_ints = 2 * HASH_CAP + (size_t)A * 16 + A + 4;
    size_t fixed_bytes = fixed_ints * 4;
    // pair capacity, clamped to what fits in ws (expected count ~5120)
    long avail_pairs = ((long)ws_size - (long)fixed_bytes) / 8;
    int cap = 16384;
    if (avail_pairs < cap) cap = (int)(avail_pairs > 0 ? avail_pairs : 0);

    // init: hkey = -1 (0xFF bytes); hval..cnt = 0
    hipMemsetAsync(hkey, 0xFF, HASH_CAP * 4, stream);
    hipMemsetAsync(hval, 0x00, (fixed_bytes - HASH_CAP * 4), stream);

    k_build<<<(A + 255) / 256, 256, 0, stream>>>(mask, A, hkey, hval);
    k_scan<<<(E + 255) / 256, 256, 0, stream>>>(dstp, E, hkey, hval, cnt, list2, cap, deg_c);
    k_edges<<<512, 256, 0, stream>>>(srcp, x, ea, w1, b1, w2, b2, cnt, list2, cap, aggr);
    k_head<<<A, 64, 0, stream>>>(mask, action, x, hkey, hval, aggr, deg_c,
                                 root, bias, fc1_w, fc1_b, fc2_w, fc2_b, fc3_w, fc3_b,
                                 (float*)d_out);
}

// Round 3
// 159.196 us; speedup vs baseline: 1.0978x; 1.0978x over previous
//
#include <hip/hip_runtime.h>
#include <math.h>

// Only out[mask_idx] (~320 agent nodes of 50000) is read downstream, so only
// edges whose dst is a masked node matter (~5120 of 800000).
//
// Round-2 post-mortem: k_scan was 53us at 0.5% HBM BW — latency/atomic bound.
// This version: bitmap membership test (6.3KB, L1-resident, no probe loop),
// int4 4-edges/thread (4x MLP), wave-ballot-aggregated single atomic per wave,
// degree counting moved to k_edges (5120 edges, not 800000 threads).
// Workspace ~36KB fixed + 64KB list, clamped to ws_size (round-1 lesson:
// overrunning ws corrupts harness pristine copies).

#define HASH_CAP  1024
#define HASH_MASK 1023
#define NBM_WORDS 1568   // ceil(50000/32)=1563, padded

__device__ __forceinline__ unsigned hash_node(int n) {
    return ((unsigned)n * 2654435761u) & HASH_MASK;
}

// Single block: zero/init all workspace state, then insert masked nodes into
// bitmap + node->slot hash. Replaces 2 memsets + k_build (fewer graph nodes).
__global__ __launch_bounds__(1024) void k_init(
    const int* __restrict__ mask_idx, int A, int nbm_words,
    int* __restrict__ hkey, int* __restrict__ hval,
    unsigned* __restrict__ bitmap, float* __restrict__ aggr_c,
    int* __restrict__ deg_c, int* __restrict__ cnt) {
    int t = threadIdx.x;
    for (int i = t; i < HASH_CAP; i += 1024) { hkey[i] = -1; hval[i] = 0; }
    for (int i = t; i < nbm_words; i += 1024) bitmap[i] = 0u;
    for (int i = t; i < A * 16; i += 1024) aggr_c[i] = 0.f;
    for (int i = t; i < A; i += 1024) deg_c[i] = 0;
    if (t == 0) *cnt = 0;
    __syncthreads();
    if (t < A) {
        int node = mask_idx[t];
        atomicOr(&bitmap[node >> 5], 1u << (node & 31));
        unsigned h = hash_node(node);
        while (true) {
            int old = atomicCAS(&hkey[h], -1, node);
            if (old == -1) { hval[h] = t; break; }
            if (old == node) break;          // duplicate node: share winner's slot
            h = (h + 1) & HASH_MASK;
        }
    }
}

// Scan all edges (4 per thread, int4); compact flagged edge ids with one
// wave-aggregated atomic per wave.
__global__ __launch_bounds__(256) void k_scan(
    const int4* __restrict__ dst4, int nquad,
    const unsigned* __restrict__ bitmap,
    int* __restrict__ cnt, int* __restrict__ list, int cap) {
    int t = blockIdx.x * 256 + threadIdx.x;
    bool in = (t < nquad);          // E%256==0 -> waves are all-active or all-idle
    int4 d = make_int4(0, 0, 0, 0);
    if (in) d = dst4[t];
    int f0 = 0, f1 = 0, f2 = 0, f3 = 0;
    if (in) {
        unsigned w0 = bitmap[d.x >> 5];
        unsigned w1 = bitmap[d.y >> 5];
        unsigned w2 = bitmap[d.z >> 5];
        unsigned w3 = bitmap[d.w >> 5];
        f0 = (w0 >> (d.x & 31)) & 1;
        f1 = (w1 >> (d.y & 31)) & 1;
        f2 = (w2 >> (d.z & 31)) & 1;
        f3 = (w3 >> (d.w & 31)) & 1;
    }
    unsigned long long m0 = __ballot(f0);
    unsigned long long m1 = __ballot(f1);
    unsigned long long m2 = __ballot(f2);
    unsigned long long m3 = __ballot(f3);
    int c0 = __popcll(m0), c1 = __popcll(m1), c2 = __popcll(m2), c3 = __popcll(m3);
    int tot = c0 + c1 + c2 + c3;
    if (tot == 0) return;
    int lane = threadIdx.x & 63;
    int base = 0;
    if (lane == 0) base = atomicAdd(cnt, tot);
    base = __shfl(base, 0, 64);
    unsigned long long lt = (lane == 0) ? 0ull : (~0ull >> (64 - lane));
    int e0 = 4 * t;
    if (f0) { int p = base + __popcll(m0 & lt);                if (p < cap) list[p] = e0;     }
    if (f1) { int p = base + c0 + __popcll(m1 & lt);           if (p < cap) list[p] = e0 + 1; }
    if (f2) { int p = base + c0 + c1 + __popcll(m2 & lt);      if (p < cap) list[p] = e0 + 2; }
    if (f3) { int p = base + c0 + c1 + c2 + __popcll(m3 & lt); if (p < cap) list[p] = e0 + 3; }
}

// Process compacted active edges. Block = 256 threads = 16 edges x 16 out-lanes.
__global__ __launch_bounds__(256) void k_edges(
    const int* __restrict__ srcp, const int* __restrict__ dstp,
    const float* __restrict__ x, const float* __restrict__ edge_attr,
    const float* __restrict__ w1, const float* __restrict__ b1,
    const float* __restrict__ w2, const float* __restrict__ b2,
    const int* __restrict__ hkey, const int* __restrict__ hval,
    const int* __restrict__ cnt, const int* __restrict__ list, int cap,
    float* __restrict__ aggr_c, int* __restrict__ deg_c) {
    __shared__ float s_w2[4096];   // [16 j][256 io]
    __shared__ float s_b2[256];
    __shared__ float s_w1[128];    // [8 k][16 j]
    __shared__ float s_b1[16];
    __shared__ float s_ea[16][8];
    __shared__ float s_x[16][16];
    __shared__ float s_h[16][16];
    __shared__ int   s_e[16], s_slot[16];

    int tid = threadIdx.x;
    int n = *cnt; if (n > cap) n = cap;
    if ((int)(blockIdx.x * 16) >= n) return;   // uniform early-exit for idle blocks

    for (int k = tid; k < 4096; k += 256) s_w2[k] = w2[k];
    s_b2[tid] = b2[tid];
    if (tid < 128) s_w1[tid] = w1[tid];
    if (tid < 16)  s_b1[tid] = b1[tid];
    __syncthreads();

    int el = tid >> 4;     // edge slot 0..15
    int o  = tid & 15;     // output channel 0..15

    for (int base = blockIdx.x * 16; base < n; base += gridDim.x * 16) {
        if (o == 0) {
            int idx = base + el;
            if (idx < n) {
                int e = list[idx];
                s_e[el] = e;
                int dn = dstp[e];
                unsigned h = hash_node(dn);
                while (hkey[h] != dn) h = (h + 1) & HASH_MASK;
                int s = hval[h];
                s_slot[el] = s;
                atomicAdd(&deg_c[s], 1);   // each flagged edge counted exactly once
            } else s_e[el] = -1;
        }
        __syncthreads();
        int e = s_e[el];
        bool valid = (e >= 0);
        if (valid) {
            if (o < 8) s_ea[el][o] = edge_attr[(long)e * 8 + o];
            s_x[el][o] = x[(long)srcp[e] * 16 + o];
        }
        __syncthreads();
        if (valid) {
            // h[el][o] = relu(b1[o] + ea . w1[:,o])
            float hj = s_b1[o];
            #pragma unroll
            for (int k = 0; k < 8; ++k) hj += s_ea[el][k] * s_w1[k * 16 + o];
            s_h[el][o] = hj > 0.f ? hj : 0.f;
        }
        __syncthreads();
        if (valid) {
            float hr[16], xr[16];
            #pragma unroll
            for (int j = 0; j < 16; ++j) hr[j] = s_h[el][j];
            #pragma unroll
            for (int i = 0; i < 16; ++i) xr[i] = s_x[el][i];
            // msg[o] = sum_i x_i * (b2[i,o] + sum_j h_j * w2[j, i*16+o])
            float m = 0.f;
            #pragma unroll
            for (int i = 0; i < 16; ++i) {
                float tacc = s_b2[i * 16 + o];
                #pragma unroll
                for (int j = 0; j < 16; ++j) tacc += hr[j] * s_w2[j * 256 + i * 16 + o];
                m += xr[i] * tacc;
            }
            atomicAdd(&aggr_c[s_slot[el] * 16 + o], m);
        }
        __syncthreads();
    }
}

// One block (1 wave, 64 threads) per agent: combine + 3-layer ELU MLP head.
__global__ __launch_bounds__(64) void k_head(
    const int* __restrict__ mask_idx, const float* __restrict__ action,
    const float* __restrict__ x,
    const int* __restrict__ hkey, const int* __restrict__ hval,
    const float* __restrict__ aggr_c, const int* __restrict__ deg_c,
    const float* __restrict__ root, const float* __restrict__ bias,
    const float* __restrict__ fc1_w, const float* __restrict__ fc1_b,
    const float* __restrict__ fc2_w, const float* __restrict__ fc2_b,
    const float* __restrict__ fc3_w, const float* __restrict__ fc3_b,
    float* __restrict__ out) {
    __shared__ float xm[17];
    __shared__ float y1[64];
    int a = blockIdx.x;
    int t = threadIdx.x;
    int node = mask_idx[a];
    unsigned h = hash_node(node);
    int s;
    while (true) {
        int k = hkey[h];
        if (k == node) { s = hval[h]; break; }
        h = (h + 1) & HASH_MASK;
    }
    if (t < 16) {
        float r = bias[t];
        #pragma unroll
        for (int i = 0; i < 16; ++i) r += x[(long)node * 16 + i] * root[i * 16 + t];
        float dg = (float)deg_c[s];
        if (dg < 1.f) dg = 1.f;
        xm[t] = aggr_c[s * 16 + t] / dg + r;
    } else if (t == 16) {
        xm[16] = action[a];
    }
    __syncthreads();
    float v = fc1_b[t];
    #pragma unroll
    for (int k = 0; k < 17; ++k) v += xm[k] * fc1_w[k * 64 + t];
    v = v > 0.f ? v : expm1f(v);
    y1[t] = v;
    __syncthreads();
    float u = fc2_b[t];
    #pragma unroll
    for (int j = 0; j < 64; ++j) u += y1[j] * fc2_w[j * 64 + t];
    u = u > 0.f ? u : expm1f(u);
    float p = u * fc3_w[t];
    #pragma unroll
    for (int off = 32; off > 0; off >>= 1) p += __shfl_down(p, off, 64);
    if (t == 0) out[a] = p + fc3_b[0];
}

extern "C" void kernel_launch(void* const* d_in, const int* in_sizes, int n_in,
                              void* d_out, int out_size, void* d_ws, size_t ws_size,
                              hipStream_t stream) {
    const float* x      = (const float*)d_in[0];
    const int*   ei     = (const int*)  d_in[1];
    const float* ea     = (const float*)d_in[2];
    const int*   mask   = (const int*)  d_in[3];
    const float* action = (const float*)d_in[4];
    // d_in[5] = B (unused)
    const float* w1     = (const float*)d_in[6];
    const float* b1     = (const float*)d_in[7];
    const float* w2     = (const float*)d_in[8];
    const float* b2     = (const float*)d_in[9];
    const float* root   = (const float*)d_in[10];
    const float* bias   = (const float*)d_in[11];
    const float* fc1_w  = (const float*)d_in[12];
    const float* fc1_b  = (const float*)d_in[13];
    const float* fc2_w  = (const float*)d_in[14];
    const float* fc2_b  = (const float*)d_in[15];
    const float* fc3_w  = (const float*)d_in[16];
    const float* fc3_b  = (const float*)d_in[17];

    const int E = in_sizes[2] / 8;    // 800000
    const int A = in_sizes[4];        // 320

    const int* srcp = ei;
    const int* dstp = ei + E;

    // Workspace layout (ints):
    // [hkey 1024][hval 1024][bitmap NBM_WORDS][aggr_c A*16 f32][deg_c A][cnt 4][list cap]
    int*      hkey   = (int*)d_ws;
    int*      hval   = hkey + HASH_CAP;
    unsigned* bitmap = (unsigned*)(hval + HASH_CAP);
    float*    aggr   = (float*)(bitmap + NBM_WORDS);
    int*      deg_c  = (int*)(aggr + (size_t)A * 16);
    int*      cnt    = deg_c + A;
    int*      list   = cnt + 4;

    size_t fixed_ints  = 2 * HASH_CAP + NBM_WORDS + (size_t)A * 16 + A + 4;
    size_t fixed_bytes = fixed_ints * 4;
    long avail = ((long)ws_size - (long)fixed_bytes) / 4;
    int cap = 16384;                         // expected ~5120 flagged edges
    if (avail < cap) cap = (int)(avail > 0 ? avail : 0);

    const int nquad = E / 4;                 // E % 4 == 0 (800000)

    k_init<<<1, 1024, 0, stream>>>(mask, A, NBM_WORDS, hkey, hval, bitmap, aggr, deg_c, cnt);
    k_scan<<<(nquad + 255) / 256, 256, 0, stream>>>((const int4*)dstp, nquad, bitmap, cnt, list, cap);
    k_edges<<<512, 256, 0, stream>>>(srcp, dstp, x, ea, w1, b1, w2, b2,
                                     hkey, hval, cnt, list, cap, aggr, deg_c);
    k_head<<<A, 64, 0, stream>>>(mask, action, x, hkey, hval, aggr, deg_c,
                                 root, bias, fc1_w, fc1_b, fc2_w, fc2_b, fc3_w, fc3_b,
                                 (float*)d_out);
}

// Round 4
// 154.950 us; speedup vs baseline: 1.1279x; 1.0274x over previous
//
#include <hip/hip_runtime.h>
#include <math.h>

// Only out[mask_idx] (~320 agent nodes of 50000) is read downstream, so only
// edges whose dst is a masked node matter (~5120 of 800000). Compact those,
// skip 99.4% of the reference's work.
//
// Round-3 post-mortem: timed window is dominated by the HARNESS reset
// (256 MiB d_ws poison = 43.6us fill @ 6.2 TB/s + ~20 restore dispatches);
// our kernels no longer appear in top-5. This round minimizes the
// controllable slice: k_init and the node->slot hash are gone — the
// membership bitmap is built redundantly per scan block in LDS (6.3 KB,
// ~100ns), and slot resolution scans the 320-entry mask list directly.
// Workspace: 21 KB fixed + 64 KB list (round-1 lesson: never overrun ws).

#define NBM_WORDS 1568   // ceil(50000/32)=1563, padded to 32B

// Scan all edges (4/thread, int4); LDS bitmap membership; compact flagged
// edge ids with one wave-aggregated atomic per wave.
__global__ __launch_bounds__(256) void k_scan(
    const int4* __restrict__ dst4, int nquad,
    const int* __restrict__ mask_idx, int A,
    int* __restrict__ cnt, int* __restrict__ list, int cap) {
    __shared__ unsigned bm[NBM_WORDS];
    int tid = threadIdx.x;
    for (int i = tid; i < NBM_WORDS; i += 256) bm[i] = 0u;
    __syncthreads();
    for (int a = tid; a < A; a += 256) {
        int node = mask_idx[a];
        atomicOr(&bm[node >> 5], 1u << (node & 31));
    }
    __syncthreads();

    int t = blockIdx.x * 256 + tid;
    bool in = (t < nquad);
    int4 d = make_int4(0, 0, 0, 0);
    if (in) d = dst4[t];
    int f0 = 0, f1 = 0, f2 = 0, f3 = 0;
    if (in) {
        f0 = (bm[d.x >> 5] >> (d.x & 31)) & 1;
        f1 = (bm[d.y >> 5] >> (d.y & 31)) & 1;
        f2 = (bm[d.z >> 5] >> (d.z & 31)) & 1;
        f3 = (bm[d.w >> 5] >> (d.w & 31)) & 1;
    }
    unsigned long long m0 = __ballot(f0);
    unsigned long long m1 = __ballot(f1);
    unsigned long long m2 = __ballot(f2);
    unsigned long long m3 = __ballot(f3);
    int c0 = __popcll(m0), c1 = __popcll(m1), c2 = __popcll(m2), c3 = __popcll(m3);
    int tot = c0 + c1 + c2 + c3;
    if (tot == 0) return;
    int lane = tid & 63;
    int base = 0;
    if (lane == 0) base = atomicAdd(cnt, tot);
    base = __shfl(base, 0, 64);
    unsigned long long lt = (lane == 0) ? 0ull : (~0ull >> (64 - lane));
    int e0 = 4 * t;
    if (f0) { int p = base + __popcll(m0 & lt);                if (p < cap) list[p] = e0;     }
    if (f1) { int p = base + c0 + __popcll(m1 & lt);           if (p < cap) list[p] = e0 + 1; }
    if (f2) { int p = base + c0 + c1 + __popcll(m2 & lt);      if (p < cap) list[p] = e0 + 2; }
    if (f3) { int p = base + c0 + c1 + c2 + __popcll(m3 & lt); if (p < cap) list[p] = e0 + 3; }
}

// Process compacted edges. Block = 256 threads = 16 edges x 16 out-lanes.
// slot(dst) = first agent index whose mask node == dst (mask list in LDS).
__global__ __launch_bounds__(256) void k_edges(
    const int* __restrict__ srcp, const int* __restrict__ dstp,
    const float* __restrict__ x, const float* __restrict__ edge_attr,
    const float* __restrict__ w1, const float* __restrict__ b1,
    const float* __restrict__ w2, const float* __restrict__ b2,
    const int* __restrict__ mask_idx, int A,
    const int* __restrict__ cnt, const int* __restrict__ list, int cap,
    float* __restrict__ aggr_c, int* __restrict__ deg_c) {
    __shared__ float s_w2[4096];   // [16 j][256 io]
    __shared__ float s_b2[256];
    __shared__ float s_w1[128];    // [8 k][16 j]
    __shared__ float s_b1[16];
    __shared__ int   s_mask[512];  // A <= 512
    __shared__ float s_ea[16][8];
    __shared__ float s_x[16][16];
    __shared__ float s_h[16][16];
    __shared__ int   s_e[16], s_dst[16], s_slot[16];

    int tid = threadIdx.x;
    int n = *cnt; if (n > cap) n = cap;
    if ((int)(blockIdx.x * 16) >= n) return;   // uniform early-exit

    for (int k = tid; k < 4096; k += 256) s_w2[k] = w2[k];
    s_b2[tid] = b2[tid];
    if (tid < 128) s_w1[tid] = w1[tid];
    if (tid < 16)  s_b1[tid] = b1[tid];
    for (int a = tid; a < A; a += 256) s_mask[a] = mask_idx[a];
    __syncthreads();

    int el = tid >> 4;     // edge slot 0..15
    int o  = tid & 15;     // output channel 0..15

    for (int base = blockIdx.x * 16; base < n; base += gridDim.x * 16) {
        if (o == 0) {
            int idx = base + el;
            if (idx < n) {
                int e = list[idx];
                s_e[el] = e;
                s_dst[el] = dstp[e];
            } else s_e[el] = -1;
            s_slot[el] = 0x7fffffff;
        }
        __syncthreads();
        int e = s_e[el];
        bool valid = (e >= 0);
        if (valid) {
            // rep-slot search: 16 lanes scan the mask list for first match
            int dn = s_dst[el];
            int best = 0x7fffffff;
            for (int a = o; a < A; a += 16)
                if (s_mask[a] == dn && a < best) best = a;
            if (best != 0x7fffffff) atomicMin(&s_slot[el], best);
            if (o < 8) s_ea[el][o] = edge_attr[(long)e * 8 + o];
            s_x[el][o] = x[(long)srcp[e] * 16 + o];
        }
        __syncthreads();
        if (valid) {
            if (o == 0) atomicAdd(&deg_c[s_slot[el]], 1);
            // h[el][o] = relu(b1[o] + ea . w1[:,o])
            float hj = s_b1[o];
            #pragma unroll
            for (int k = 0; k < 8; ++k) hj += s_ea[el][k] * s_w1[k * 16 + o];
            s_h[el][o] = hj > 0.f ? hj : 0.f;
        }
        __syncthreads();
        if (valid) {
            float hr[16], xr[16];
            #pragma unroll
            for (int j = 0; j < 16; ++j) hr[j] = s_h[el][j];
            #pragma unroll
            for (int i = 0; i < 16; ++i) xr[i] = s_x[el][i];
            // msg[o] = sum_i x_i * (b2[i,o] + sum_j h_j * w2[j, i*16+o])
            float m = 0.f;
            #pragma unroll
            for (int i = 0; i < 16; ++i) {
                float tacc = s_b2[i * 16 + o];
                #pragma unroll
                for (int j = 0; j < 16; ++j) tacc += hr[j] * s_w2[j * 256 + i * 16 + o];
                m += xr[i] * tacc;
            }
            atomicAdd(&aggr_c[s_slot[el] * 16 + o], m);
        }
        __syncthreads();
    }
}

// One block (1 wave) per agent: combine + 3-layer ELU MLP head.
__global__ __launch_bounds__(64) void k_head(
    const int* __restrict__ mask_idx, int A, const float* __restrict__ action,
    const float* __restrict__ x,
    const float* __restrict__ aggr_c, const int* __restrict__ deg_c,
    const float* __restrict__ root, const float* __restrict__ bias,
    const float* __restrict__ fc1_w, const float* __restrict__ fc1_b,
    const float* __restrict__ fc2_w, const float* __restrict__ fc2_b,
    const float* __restrict__ fc3_w, const float* __restrict__ fc3_b,
    float* __restrict__ out) {
    __shared__ float xm[17];
    __shared__ float y1[64];
    int a = blockIdx.x;
    int t = threadIdx.x;
    int node = mask_idx[a];
    // rep slot = first agent index with this node (handles duplicate agents)
    int best = 0x7fffffff;
    for (int i = t; i < A; i += 64) {
        if (mask_idx[i] == node && i < best) best = i;
    }
    #pragma unroll
    for (int off = 32; off > 0; off >>= 1) {
        int o2 = __shfl_xor(best, off, 64);
        if (o2 < best) best = o2;
    }
    int s = best;
    if (t < 16) {
        float r = bias[t];
        #pragma unroll
        for (int i = 0; i < 16; ++i) r += x[(long)node * 16 + i] * root[i * 16 + t];
        float dg = (float)deg_c[s];
        if (dg < 1.f) dg = 1.f;
        xm[t] = aggr_c[s * 16 + t] / dg + r;
    } else if (t == 16) {
        xm[16] = action[a];
    }
    __syncthreads();
    float v = fc1_b[t];
    #pragma unroll
    for (int k = 0; k < 17; ++k) v += xm[k] * fc1_w[k * 64 + t];
    v = v > 0.f ? v : expm1f(v);
    y1[t] = v;
    __syncthreads();
    float u = fc2_b[t];
    #pragma unroll
    for (int j = 0; j < 64; ++j) u += y1[j] * fc2_w[j * 64 + t];
    u = u > 0.f ? u : expm1f(u);
    float p = u * fc3_w[t];
    #pragma unroll
    for (int off = 32; off > 0; off >>= 1) p += __shfl_down(p, off, 64);
    if (t == 0) out[a] = p + fc3_b[0];
}

extern "C" void kernel_launch(void* const* d_in, const int* in_sizes, int n_in,
                              void* d_out, int out_size, void* d_ws, size_t ws_size,
                              hipStream_t stream) {
    const float* x      = (const float*)d_in[0];
    const int*   ei     = (const int*)  d_in[1];
    const float* ea     = (const float*)d_in[2];
    const int*   mask   = (const int*)  d_in[3];
    const float* action = (const float*)d_in[4];
    // d_in[5] = B (unused)
    const float* w1     = (const float*)d_in[6];
    const float* b1     = (const float*)d_in[7];
    const float* w2     = (const float*)d_in[8];
    const float* b2     = (const float*)d_in[9];
    const float* root   = (const float*)d_in[10];
    const float* bias   = (const float*)d_in[11];
    const float* fc1_w  = (const float*)d_in[12];
    const float* fc1_b  = (const float*)d_in[13];
    const float* fc2_w  = (const float*)d_in[14];
    const float* fc2_b  = (const float*)d_in[15];
    const float* fc3_w  = (const float*)d_in[16];
    const float* fc3_b  = (const float*)d_in[17];

    const int E = in_sizes[2] / 8;    // 800000
    const int A = in_sizes[4];        // 320

    const int* srcp = ei;
    const int* dstp = ei + E;

    // Workspace (ints): [cnt 4][deg_c A][aggr_c A*16 f32][list cap]
    int*   cnt   = (int*)d_ws;
    int*   deg_c = cnt + 4;
    float* aggr  = (float*)(deg_c + A);
    int*   list  = (int*)(aggr + (size_t)A * 16);

    size_t fixed_ints  = 4 + (size_t)A + (size_t)A * 16;
    size_t fixed_bytes = fixed_ints * 4;
    long avail = ((long)ws_size - (long)fixed_bytes) / 4;
    int cap = 16384;                  // expected ~5120 flagged edges
    if (avail < cap) cap = (int)(avail > 0 ? avail : 0);

    const int nquad = E / 4;          // E % 4 == 0

    hipMemsetAsync(d_ws, 0, fixed_bytes, stream);
    k_scan<<<(nquad + 255) / 256, 256, 0, stream>>>((const int4*)dstp, nquad,
                                                    mask, A, cnt, list, cap);
    k_edges<<<512, 256, 0, stream>>>(srcp, dstp, x, ea, w1, b1, w2, b2,
                                     mask, A, cnt, list, cap, aggr, deg_c);
    k_head<<<A, 64, 0, stream>>>(mask, A, action, x, aggr, deg_c,
                                 root, bias, fc1_w, fc1_b, fc2_w, fc2_b, fc3_w, fc3_b,
                                 (float*)d_out);
}

// Round 5
// 122.891 us; speedup vs baseline: 1.4221x; 1.2609x over previous
//
#include <hip/hip_runtime.h>
#include <math.h>

// Only out[mask_idx] (~320 agent nodes of 50000) is read downstream, so only
// edges whose dst is a masked node matter (~5120 of 800000).
//
// Round-4 post-mortem: k_scan was still ~30us — bound by the SINGLE global
// cnt atomicAdd (~3128 same-address L2 RMWs x ~25cyc). This round removes the
// global counter and the compacted list entirely: scan+edges are FUSED. Each
// block finds its flagged edges via an LDS bitmap, queues them in LDS (LDS
// atomics, no L2 round-trip), and processes them in-place with staged weights.
// Global atomics that remain go to 320 distinct agent slots (uncontended).
// Workspace: 21.3 KB (aggr_c + deg_c) — round-1 lesson: never overrun ws.

#define NBM_WORDS 1568   // ceil(50000/32)=1563, padded
#define QCAP      1024   // block covers 1024 edges -> queue can never overflow
#define AMAX      512    // A <= 512

__global__ __launch_bounds__(256) void k_fused(
    const int* __restrict__ srcp, const int* __restrict__ dstp,
    const int4* __restrict__ dst4, int nquad, int E,
    const float* __restrict__ x, const float* __restrict__ edge_attr,
    const float* __restrict__ w1, const float* __restrict__ b1,
    const float* __restrict__ w2, const float* __restrict__ b2,
    const int* __restrict__ mask_idx, int A,
    float* __restrict__ aggr_c, int* __restrict__ deg_c) {
    __shared__ unsigned bm[NBM_WORDS];
    __shared__ float s_w2[4096];   // [16 j][256 io]
    __shared__ float s_b2[256];
    __shared__ float s_w1[128];    // [8 k][16 j]
    __shared__ float s_b1[16];
    __shared__ int   s_mask[AMAX];
    __shared__ int   s_qe[QCAP];   // queued edge ids
    __shared__ int   s_qd[QCAP];   // their dst nodes
    __shared__ int   s_qcnt;
    __shared__ float s_ea[16][8];
    __shared__ float s_x[16][16];
    __shared__ float s_h[16][16];
    __shared__ int   s_slot[16];

    int tid = threadIdx.x;
    if (tid == 0) s_qcnt = 0;
    for (int i = tid; i < NBM_WORDS; i += 256) bm[i] = 0u;
    // stage weights concurrently with bitmap zeroing (independent)
    for (int k = tid; k < 4096; k += 256) s_w2[k] = w2[k];
    s_b2[tid] = b2[tid];
    if (tid < 128) s_w1[tid] = w1[tid];
    if (tid < 16)  s_b1[tid] = b1[tid];
    __syncthreads();                    // bm zeroed before inserts
    for (int a = tid; a < A; a += 256) {
        int node = mask_idx[a];
        s_mask[a] = node;
        atomicOr(&bm[node >> 5], 1u << (node & 31));
    }
    __syncthreads();

    // Phase 2: scan this block's 1024 edges, queue flagged ones in LDS.
    int q = blockIdx.x * 256 + tid;
    if (q < nquad) {
        int4 d = dst4[q];
        int e0 = q * 4;
        if ((bm[d.x >> 5] >> (d.x & 31)) & 1) { int p = atomicAdd(&s_qcnt, 1); if (p < QCAP) { s_qe[p] = e0;     s_qd[p] = d.x; } }
        if ((bm[d.y >> 5] >> (d.y & 31)) & 1) { int p = atomicAdd(&s_qcnt, 1); if (p < QCAP) { s_qe[p] = e0 + 1; s_qd[p] = d.y; } }
        if ((bm[d.z >> 5] >> (d.z & 31)) & 1) { int p = atomicAdd(&s_qcnt, 1); if (p < QCAP) { s_qe[p] = e0 + 2; s_qd[p] = d.z; } }
        if ((bm[d.w >> 5] >> (d.w & 31)) & 1) { int p = atomicAdd(&s_qcnt, 1); if (p < QCAP) { s_qe[p] = e0 + 3; s_qd[p] = d.w; } }
    }
    // tail edges if E % 4 != 0 (none for E=800000; safety)
    if (blockIdx.x == 0 && tid == 0) {
        for (int e = nquad * 4; e < E; ++e) {
            int dn = dstp[e];
            if ((bm[dn >> 5] >> (dn & 31)) & 1) {
                int p = atomicAdd(&s_qcnt, 1);
                if (p < QCAP) { s_qe[p] = e; s_qd[p] = dn; }
            }
        }
    }
    __syncthreads();
    int nq = s_qcnt; if (nq > QCAP) nq = QCAP;
    if (nq == 0) return;                // uniform

    // Phase 3: process queue, 16 edges x 16 out-lanes per chunk.
    int el = tid >> 4;     // edge slot 0..15
    int o  = tid & 15;     // output channel 0..15
    for (int base = 0; base < nq; base += 16) {
        int idx = base + el;
        bool valid = (idx < nq);
        int e = valid ? s_qe[idx] : -1;
        if (o == 0) s_slot[el] = 0x7fffffff;
        __syncthreads();
        if (valid) {
            // rep slot = first agent index whose node == dst (16-lane search)
            int dn = s_qd[idx];
            int best = 0x7fffffff;
            for (int a = o; a < A; a += 16)
                if (s_mask[a] == dn && a < best) best = a;
            if (best != 0x7fffffff) atomicMin(&s_slot[el], best);
            if (o < 8) s_ea[el][o] = edge_attr[(long)e * 8 + o];
            s_x[el][o] = x[(long)srcp[e] * 16 + o];
        }
        __syncthreads();
        if (valid) {
            if (o == 0) atomicAdd(&deg_c[s_slot[el]], 1);
            // h[el][o] = relu(b1[o] + ea . w1[:,o])
            float hj = s_b1[o];
            #pragma unroll
            for (int k = 0; k < 8; ++k) hj += s_ea[el][k] * s_w1[k * 16 + o];
            s_h[el][o] = hj > 0.f ? hj : 0.f;
        }
        __syncthreads();
        if (valid) {
            float hr[16], xr[16];
            #pragma unroll
            for (int j = 0; j < 16; ++j) hr[j] = s_h[el][j];
            #pragma unroll
            for (int i = 0; i < 16; ++i) xr[i] = s_x[el][i];
            // msg[o] = sum_i x_i * (b2[i,o] + sum_j h_j * w2[j, i*16+o])
            float m = 0.f;
            #pragma unroll
            for (int i = 0; i < 16; ++i) {
                float tacc = s_b2[i * 16 + o];
                #pragma unroll
                for (int j = 0; j < 16; ++j) tacc += hr[j] * s_w2[j * 256 + i * 16 + o];
                m += xr[i] * tacc;
            }
            atomicAdd(&aggr_c[s_slot[el] * 16 + o], m);
        }
        __syncthreads();
    }
}

// One block (1 wave) per agent: combine + 3-layer ELU MLP head.
__global__ __launch_bounds__(64) void k_head(
    const int* __restrict__ mask_idx, int A, const float* __restrict__ action,
    const float* __restrict__ x,
    const float* __restrict__ aggr_c, const int* __restrict__ deg_c,
    const float* __restrict__ root, const float* __restrict__ bias,
    const float* __restrict__ fc1_w, const float* __restrict__ fc1_b,
    const float* __restrict__ fc2_w, const float* __restrict__ fc2_b,
    const float* __restrict__ fc3_w, const float* __restrict__ fc3_b,
    float* __restrict__ out) {
    __shared__ float xm[17];
    __shared__ float y1[64];
    int a = blockIdx.x;
    int t = threadIdx.x;
    int node = mask_idx[a];
    // rep slot = first agent index with this node (duplicate agents share)
    int best = 0x7fffffff;
    for (int i = t; i < A; i += 64)
        if (mask_idx[i] == node && i < best) best = i;
    #pragma unroll
    for (int off = 32; off > 0; off >>= 1) {
        int o2 = __shfl_xor(best, off, 64);
        if (o2 < best) best = o2;
    }
    int s = best;
    if (t < 16) {
        float r = bias[t];
        #pragma unroll
        for (int i = 0; i < 16; ++i) r += x[(long)node * 16 + i] * root[i * 16 + t];
        float dg = (float)deg_c[s];
        if (dg < 1.f) dg = 1.f;
        xm[t] = aggr_c[s * 16 + t] / dg + r;
    } else if (t == 16) {
        xm[16] = action[a];
    }
    __syncthreads();
    float v = fc1_b[t];
    #pragma unroll
    for (int k = 0; k < 17; ++k) v += xm[k] * fc1_w[k * 64 + t];
    v = v > 0.f ? v : expm1f(v);
    y1[t] = v;
    __syncthreads();
    float u = fc2_b[t];
    #pragma unroll
    for (int j = 0; j < 64; ++j) u += y1[j] * fc2_w[j * 64 + t];
    u = u > 0.f ? u : expm1f(u);
    float p = u * fc3_w[t];
    #pragma unroll
    for (int off = 32; off > 0; off >>= 1) p += __shfl_down(p, off, 64);
    if (t == 0) out[a] = p + fc3_b[0];
}

extern "C" void kernel_launch(void* const* d_in, const int* in_sizes, int n_in,
                              void* d_out, int out_size, void* d_ws, size_t ws_size,
                              hipStream_t stream) {
    const float* x      = (const float*)d_in[0];
    const int*   ei     = (const int*)  d_in[1];
    const float* ea     = (const float*)d_in[2];
    const int*   mask   = (const int*)  d_in[3];
    const float* action = (const float*)d_in[4];
    // d_in[5] = B (unused)
    const float* w1     = (const float*)d_in[6];
    const float* b1     = (const float*)d_in[7];
    const float* w2     = (const float*)d_in[8];
    const float* b2     = (const float*)d_in[9];
    const float* root   = (const float*)d_in[10];
    const float* bias   = (const float*)d_in[11];
    const float* fc1_w  = (const float*)d_in[12];
    const float* fc1_b  = (const float*)d_in[13];
    const float* fc2_w  = (const float*)d_in[14];
    const float* fc2_b  = (const float*)d_in[15];
    const float* fc3_w  = (const float*)d_in[16];
    const float* fc3_b  = (const float*)d_in[17];

    const int E = in_sizes[2] / 8;    // 800000
    const int A = in_sizes[4];        // 320

    const int* srcp = ei;
    const int* dstp = ei + E;

    // Workspace: [aggr_c A*16 f32][deg_c A i32]  (21.3 KB total)
    float* aggr  = (float*)d_ws;
    int*   deg_c = (int*)(aggr + (size_t)A * 16);
    size_t fixed_bytes = (size_t)A * 16 * 4 + (size_t)A * 4;

    const int nquad = E / 4;
    const int nblocks = (nquad + 255) / 256;

    hipMemsetAsync(d_ws, 0, fixed_bytes, stream);
    k_fused<<<nblocks, 256, 0, stream>>>(srcp, dstp, (const int4*)dstp, nquad, E,
                                         x, ea, w1, b1, w2, b2, mask, A, aggr, deg_c);
    k_head<<<A, 64, 0, stream>>>(mask, A, action, x, aggr, deg_c,
                                 root, bias, fc1_w, fc1_b, fc2_w, fc2_b, fc3_w, fc3_b,
                                 (float*)d_out);
}